// Round 2
// baseline (138.442 us; speedup 1.0000x reference)
//
#include <hip/hip_runtime.h>
#include <hip/hip_bf16.h>

using bf16x8 = __attribute__((ext_vector_type(8))) short;
using f32x4  = __attribute__((ext_vector_type(4))) float;

__device__ __forceinline__ unsigned short f2bf(float x) {
    unsigned int u = __float_as_uint(x);
    return (unsigned short)((u + 0x7FFFu + ((u >> 16) & 1u)) >> 16);
}

// -------------------------------------------------------------------------
// K0: pack text_embeddings [91][512] f32 -> [96][512] bf16 (rows 91..95 = 0)
// -------------------------------------------------------------------------
__global__ __launch_bounds__(256)
void k_prep(const float* __restrict__ te, unsigned short* __restrict__ te_bf) {
    const int r = blockIdx.x;            // 0..95
    for (int i = threadIdx.x; i < 512; i += 256) {
        const float v = (r < 91) ? te[(size_t)r * 512 + i] : 0.f;
        te_bf[(size_t)r * 512 + i] = f2bf(v);
    }
}

// -------------------------------------------------------------------------
// Fused: per block = 16 n-rows x all 1600 m
//  ph1: 4 waves K-split MFMA -> partial dots in LDS (+ sumsq)
//  ph2: reduce + focal + embed-cost -> cc_s[16][96]
//  ph3: stage targets (raw cxcywh + id) over the acc region (union)
//  ph4: cost loop, float4 stores
// -------------------------------------------------------------------------
constexpr int NT = 16;

union SmemU {
    float acc[4][NT * 96];                                    // 24576 B
    struct {
        float cx[1600], cy[1600], w[1600], h[1600];
        unsigned short id[1600];
    } t;                                                      // 28800 B
};

__device__ __forceinline__ float cost_one(
    float pcx, float pcy, float pw, float ph,
    float px0, float py0, float px1, float py1, float pa,
    float tcx, float tcy, float tw, float th,
    float tx0, float ty0, float tx1, float ty1, float ta, float cc)
{
    const float l1 = fabsf(pcx - tcx) + fabsf(pcy - tcy) + fabsf(pw - tw) + fabsf(ph - th);
    const float ix0 = fmaxf(px0, tx0), iy0 = fmaxf(py0, ty0);
    const float ix1 = fminf(px1, tx1), iy1 = fminf(py1, ty1);
    const float iw = fmaxf(ix1 - ix0, 0.f), ih = fmaxf(iy1 - iy0, 0.f);
    const float inter = iw * ih;
    const float uni = pa + ta - inter;
    const float ex0 = fminf(px0, tx0), ey0 = fminf(py0, ty0);
    const float ex1 = fmaxf(px1, tx1), ey1 = fmaxf(py1, ty1);
    const float ew = fmaxf(ex1 - ex0, 0.f), eh = fmaxf(ey1 - ey0, 0.f);
    const float ae = ew * eh;
    const float giou = __fdividef(inter, uni) - __fdividef(ae - uni, ae);
    return cc + l1 - giou;
}

__global__ __launch_bounds__(256, 4)
void k_fused(const float* __restrict__ logits,     // [16384][91]
             const float* __restrict__ pboxes,     // [16384][4]
             const float* __restrict__ embed,      // [16384][512]
             const unsigned short* __restrict__ te_bf, // [96][512] bf16
             const int* __restrict__ tids,         // [1600]
             const float* __restrict__ tboxes,     // [1600][4]
             float* __restrict__ out)              // [16384][1600]
{
    __shared__ SmemU u;
    __shared__ float cc_s[NT * 96];
    __shared__ float p_s[NT * 12];
    __shared__ float sq_s[4][16];

    const int tid  = threadIdx.x;
    const int lane = tid & 63;
    const int wv   = tid >> 6;       // K-chunk index 0..3
    const int r16  = lane & 15;
    const int q    = lane >> 4;
    const int n0   = blockIdx.x * NT;

    // ---- phase 1: partial dots over K-chunk [wv*128, wv*128+128)
    f32x4 acc[6];
#pragma unroll
    for (int j = 0; j < 6; ++j) acc[j] = (f32x4){0.f, 0.f, 0.f, 0.f};
    float sumsq = 0.f;

    const float* arow = embed + (size_t)(n0 + r16) * 512 + wv * 128 + q * 8;
#pragma unroll
    for (int ks = 0; ks < 4; ++ks) {
        const float4 a0 = *(const float4*)(arow + ks * 32);
        const float4 a1 = *(const float4*)(arow + ks * 32 + 4);
        const float fv[8] = {a0.x, a0.y, a0.z, a0.w, a1.x, a1.y, a1.z, a1.w};
        bf16x8 af;
#pragma unroll
        for (int j = 0; j < 8; ++j) {
            sumsq += fv[j] * fv[j];
            af[j] = (short)f2bf(fv[j]);
        }
#pragma unroll
        for (int ct = 0; ct < 6; ++ct) {
            const bf16x8 bfr = *(const bf16x8*)(te_bf + (size_t)(ct * 16 + r16) * 512
                                                + wv * 128 + ks * 32 + q * 8);
            acc[ct] = __builtin_amdgcn_mfma_f32_16x16x32_bf16(af, bfr, acc[ct], 0, 0, 0);
        }
    }
    sumsq += __shfl_xor(sumsq, 16);
    sumsq += __shfl_xor(sumsq, 32);
    if (lane < 16) sq_s[wv][r16] = sumsq;

#pragma unroll
    for (int ct = 0; ct < 6; ++ct)
#pragma unroll
        for (int j = 0; j < 4; ++j)
            u.acc[wv][(q * 4 + j) * 96 + ct * 16 + r16] = acc[ct][j];
    __syncthreads();

    // ---- phase 2: reduce partials + focal -> cc_s
#pragma unroll
    for (int i = 0; i < 6; ++i) {
        const int e = tid + i * 256;                 // < 1536
        const int row = e / 96, col = e - row * 96;
        float v = 0.f;
        if (col < 91) {
            const float dot = u.acc[0][e] + u.acc[1][e] + u.acc[2][e] + u.acc[3][e];
            const float rn  = rsqrtf(sq_s[0][row] + sq_s[1][row] + sq_s[2][row] + sq_s[3][row]);
            const float x = logits[(size_t)(n0 + row) * 91 + col];
            const float p = 1.f / (1.f + __expf(-x));
            const float pos = 0.25f * (1.f - p) * (1.f - p) * (-__logf(p + 1e-8f));
            const float neg = 0.75f * p * p * (-__logf(1.f - p + 1e-8f));
            v = (pos - neg) + 0.5f - 0.5f * dot * rn;
        }
        cc_s[e] = v;
    }
    __syncthreads();

    // ---- phase 3: stage targets (raw) + pred rows
    for (int m = tid; m < 1600; m += 256) {
        const float4 b = *(const float4*)(tboxes + (size_t)m * 4);
        u.t.cx[m] = b.x; u.t.cy[m] = b.y; u.t.w[m] = b.z; u.t.h[m] = b.w;
        u.t.id[m] = (unsigned short)tids[m];
    }
    if (tid < NT) {
        const float4 b = *(const float4*)(pboxes + (size_t)(n0 + tid) * 4);
        float* p = &p_s[tid * 12];
        p[0] = b.x; p[1] = b.y; p[2] = b.z; p[3] = b.w;
        p[4] = b.x - 0.5f * b.z; p[5] = b.y - 0.5f * b.w;
        p[6] = b.x + 0.5f * b.z; p[7] = b.y + 0.5f * b.w;
        p[8] = b.z * b.w;
    }
    __syncthreads();

    // ---- phase 4: cost loop
    for (int g = tid; g < 400; g += 256) {
        const int m0 = g * 4;
        const float4 mcx = *(const float4*)&u.t.cx[m0];
        const float4 mcy = *(const float4*)&u.t.cy[m0];
        const float4 mw  = *(const float4*)&u.t.w[m0];
        const float4 mh  = *(const float4*)&u.t.h[m0];
        const unsigned short* idp = &u.t.id[m0];
        const int id0 = idp[0], id1 = idp[1], id2 = idp[2], id3 = idp[3];

        const float tx0_0 = mcx.x - 0.5f * mw.x, ty0_0 = mcy.x - 0.5f * mh.x;
        const float tx1_0 = mcx.x + 0.5f * mw.x, ty1_0 = mcy.x + 0.5f * mh.x;
        const float tx0_1 = mcx.y - 0.5f * mw.y, ty0_1 = mcy.y - 0.5f * mh.y;
        const float tx1_1 = mcx.y + 0.5f * mw.y, ty1_1 = mcy.y + 0.5f * mh.y;
        const float tx0_2 = mcx.z - 0.5f * mw.z, ty0_2 = mcy.z - 0.5f * mh.z;
        const float tx1_2 = mcx.z + 0.5f * mw.z, ty1_2 = mcy.z + 0.5f * mh.z;
        const float tx0_3 = mcx.w - 0.5f * mw.w, ty0_3 = mcy.w - 0.5f * mh.w;
        const float tx1_3 = mcx.w + 0.5f * mw.w, ty1_3 = mcy.w + 0.5f * mh.w;
        const float ta0 = mw.x * mh.x, ta1 = mw.y * mh.y;
        const float ta2 = mw.z * mh.z, ta3 = mw.w * mh.w;

#pragma unroll 4
        for (int n = 0; n < NT; ++n) {
            const float4 P0 = *(const float4*)&p_s[n * 12];
            const float4 P1 = *(const float4*)&p_s[n * 12 + 4];
            const float pa = p_s[n * 12 + 8];
            const float cc0 = cc_s[n * 96 + id0];
            const float cc1 = cc_s[n * 96 + id1];
            const float cc2 = cc_s[n * 96 + id2];
            const float cc3 = cc_s[n * 96 + id3];
            float4 res;
            res.x = cost_one(P0.x, P0.y, P0.z, P0.w, P1.x, P1.y, P1.z, P1.w, pa,
                             mcx.x, mcy.x, mw.x, mh.x, tx0_0, ty0_0, tx1_0, ty1_0, ta0, cc0);
            res.y = cost_one(P0.x, P0.y, P0.z, P0.w, P1.x, P1.y, P1.z, P1.w, pa,
                             mcx.y, mcy.y, mw.y, mh.y, tx0_1, ty0_1, tx1_1, ty1_1, ta1, cc1);
            res.z = cost_one(P0.x, P0.y, P0.z, P0.w, P1.x, P1.y, P1.z, P1.w, pa,
                             mcx.z, mcy.z, mw.z, mh.z, tx0_2, ty0_2, tx1_2, ty1_2, ta2, cc2);
            res.w = cost_one(P0.x, P0.y, P0.z, P0.w, P1.x, P1.y, P1.z, P1.w, pa,
                             mcx.w, mcy.w, mw.w, mh.w, tx0_3, ty0_3, tx1_3, ty1_3, ta3, cc3);
            *(float4*)(out + (size_t)(n0 + n) * 1600 + m0) = res;
        }
    }
}

extern "C" void kernel_launch(void* const* d_in, const int* in_sizes, int n_in,
                              void* d_out, int out_size, void* d_ws, size_t ws_size,
                              hipStream_t stream) {
    const float* pred_logits = (const float*)d_in[0];   // [16,1024,91]
    const float* pred_boxes  = (const float*)d_in[1];   // [16,1024,4]
    const float* pred_embed  = (const float*)d_in[2];   // [16,1024,512]
    const float* text_emb    = (const float*)d_in[3];   // [91,512]
    const int*   tgt_ids     = (const int*)d_in[4];     // [1600]
    const float* tgt_bbox    = (const float*)d_in[5];   // [1600,4]
    float* out = (float*)d_out;                         // [16384,1600]
    unsigned short* te_bf = (unsigned short*)d_ws;      // [96][512] bf16 = 96 KB

    k_prep<<<96, 256, 0, stream>>>(text_emb, te_bf);
    k_fused<<<1024, 256, 0, stream>>>(pred_logits, pred_boxes, pred_embed,
                                      te_bf, tgt_ids, tgt_bbox, out);
}

// Round 3
// 71.761 us; speedup vs baseline: 1.9292x; 1.9292x over previous
//
#include <hip/hip_runtime.h>
#include <hip/hip_bf16.h>

using bf16x8 = __attribute__((ext_vector_type(8))) short;
using f32x4  = __attribute__((ext_vector_type(4))) float;

__device__ __forceinline__ unsigned short f2bf(float x) {
    unsigned int u = __float_as_uint(x);
    return (unsigned short)((u + 0x7FFFu + ((u >> 16) & 1u)) >> 16);
}

// -------------------------------------------------------------------------
// K0: pack text_embeddings [91][512] f32 -> [96][512] bf16 (rows 91..95 = 0)
// -------------------------------------------------------------------------
__global__ __launch_bounds__(256)
void k_prep(const float* __restrict__ te, unsigned short* __restrict__ te_bf) {
    const int r = blockIdx.x;            // 0..95
    for (int i = threadIdx.x; i < 512; i += 256) {
        const float v = (r < 91) ? te[(size_t)r * 512 + i] : 0.f;
        te_bf[(size_t)r * 512 + i] = f2bf(v);
    }
}

// -------------------------------------------------------------------------
// K1: ccombo[n][c] = focal(logits[n][c]) + 0.5*(1 - <v_norm[n], te[c]>)
// grid 1024, block 256 = 16 rows, 4 waves K-split (128 k each).
// te_bf (96 KB) stays L2-resident; no big write stream in this kernel.
// -------------------------------------------------------------------------
__global__ __launch_bounds__(256)
void k_class_embed(const float* __restrict__ logits,       // [16384][91]
                   const float* __restrict__ embed,        // [16384][512]
                   const unsigned short* __restrict__ te_bf, // [96][512] bf16
                   float* __restrict__ ccombo)             // [16384][96]
{
    __shared__ float accs[4][16 * 96];     // 24576 B
    __shared__ float sq_s[4][16];

    const int tid  = threadIdx.x;
    const int lane = tid & 63;
    const int wv   = tid >> 6;             // K-chunk 0..3
    const int r16  = lane & 15;
    const int q    = lane >> 4;
    const int n0   = blockIdx.x * 16;

    f32x4 acc[6];
#pragma unroll
    for (int j = 0; j < 6; ++j) acc[j] = (f32x4){0.f, 0.f, 0.f, 0.f};
    float sumsq = 0.f;

    const float* arow = embed + (size_t)(n0 + r16) * 512 + wv * 128 + q * 8;
#pragma unroll
    for (int ks = 0; ks < 4; ++ks) {
        const float4 a0 = *(const float4*)(arow + ks * 32);
        const float4 a1 = *(const float4*)(arow + ks * 32 + 4);
        const float fv[8] = {a0.x, a0.y, a0.z, a0.w, a1.x, a1.y, a1.z, a1.w};
        bf16x8 af;
#pragma unroll
        for (int j = 0; j < 8; ++j) {
            sumsq += fv[j] * fv[j];
            af[j] = (short)f2bf(fv[j]);
        }
#pragma unroll
        for (int ct = 0; ct < 6; ++ct) {
            const bf16x8 bfr = *(const bf16x8*)(te_bf + (size_t)(ct * 16 + r16) * 512
                                                + wv * 128 + ks * 32 + q * 8);
            acc[ct] = __builtin_amdgcn_mfma_f32_16x16x32_bf16(af, bfr, acc[ct], 0, 0, 0);
        }
    }
    sumsq += __shfl_xor(sumsq, 16);
    sumsq += __shfl_xor(sumsq, 32);
    if (lane < 16) sq_s[wv][r16] = sumsq;

#pragma unroll
    for (int ct = 0; ct < 6; ++ct)
#pragma unroll
        for (int j = 0; j < 4; ++j)
            accs[wv][(q * 4 + j) * 96 + ct * 16 + r16] = acc[ct][j];
    __syncthreads();

#pragma unroll
    for (int i = 0; i < 6; ++i) {
        const int e = tid + i * 256;                 // < 1536
        const int row = e / 96, col = e - row * 96;
        float v = 0.f;
        if (col < 91) {
            const float dot = accs[0][e] + accs[1][e] + accs[2][e] + accs[3][e];
            const float rn  = rsqrtf(sq_s[0][row] + sq_s[1][row] + sq_s[2][row] + sq_s[3][row]);
            const float x = logits[(size_t)(n0 + row) * 91 + col];
            const float p = 1.f / (1.f + __expf(-x));
            const float pos = 0.25f * (1.f - p) * (1.f - p) * (-__logf(p + 1e-8f));
            const float neg = 0.75f * p * p * (-__logf(1.f - p + 1e-8f));
            v = (pos - neg) + 0.5f - 0.5f * dot * rn;
        }
        ccombo[(size_t)n0 * 96 + e] = v;
    }
}

// -------------------------------------------------------------------------
// K2: out[n][m] = ccombo[n][id[m]] + L1 - GIoU
// grid 2048 = 1024 n-tiles x 2 m-halves; block 256 = 16 n x 800 m
// LDS ~23 KB -> 5 blocks/CU. Phase 4: single pass, thread = 4m x 16n.
// -------------------------------------------------------------------------
__device__ __forceinline__ float cost_one(
    float pcx, float pcy, float pw, float ph,
    float px0, float py0, float px1, float py1, float pa,
    float tcx, float tcy, float tw, float th,
    float tx0, float ty0, float tx1, float ty1, float ta, float cc)
{
    const float l1 = fabsf(pcx - tcx) + fabsf(pcy - tcy) + fabsf(pw - tw) + fabsf(ph - th);
    const float ix0 = fmaxf(px0, tx0), iy0 = fmaxf(py0, ty0);
    const float ix1 = fminf(px1, tx1), iy1 = fminf(py1, ty1);
    const float iw = fmaxf(ix1 - ix0, 0.f), ih = fmaxf(iy1 - iy0, 0.f);
    const float inter = iw * ih;
    const float uni = pa + ta - inter;
    const float ex0 = fminf(px0, tx0), ey0 = fminf(py0, ty0);
    const float ex1 = fmaxf(px1, tx1), ey1 = fmaxf(py1, ty1);
    const float ae = (ex1 - ex0) * (ey1 - ey0);      // always >= 0 (w,h > 0)
    // giou = inter/uni - (ae-uni)/ae  ==  [inter*ae - uni*(ae-uni)] / (uni*ae)
    const float num = inter * ae - uni * (ae - uni);
    const float g   = __fdividef(num, uni * ae);
    return cc + l1 - g;
}

__global__ __launch_bounds__(256)
void k_cost(const float* __restrict__ pboxes,   // [16384][4] cxcywh
            const float* __restrict__ tboxes,   // [1600][4]  cxcywh
            const int*   __restrict__ tids,     // [1600]
            const float* __restrict__ ccombo,   // [16384][96]
            float* __restrict__ out)            // [16384][1600]
{
    __shared__ float t_cx[800], t_cy[800], t_w[800], t_h[800];   // 12800 B
    __shared__ unsigned short t_id[800];                          // 1600 B
    __shared__ float ccT[96 * 20];                                // 7680 B (pad 20)
    __shared__ float p_s[16 * 12];                                //  768 B

    const int tid = threadIdx.x;
    const int n0     = (blockIdx.x >> 1) * 16;
    const int m0base = (blockIdx.x & 1) * 800;

    // stage targets (raw)
    for (int m = tid; m < 800; m += 256) {
        const float4 b = *(const float4*)(tboxes + (size_t)(m0base + m) * 4);
        t_cx[m] = b.x; t_cy[m] = b.y; t_w[m] = b.z; t_h[m] = b.w;
        t_id[m] = (unsigned short)tids[m0base + m];
    }
    // stage cc transposed: ccT[col][row]
    for (int i = tid; i < 1536; i += 256) {
        const int row = i / 96, col = i - row * 96;
        ccT[col * 20 + row] = ccombo[(size_t)n0 * 96 + i];
    }
    if (tid < 16) {
        const float4 b = *(const float4*)(pboxes + (size_t)(n0 + tid) * 4);
        float* p = &p_s[tid * 12];
        p[0] = b.x; p[1] = b.y; p[2] = b.z; p[3] = b.w;
        p[4] = b.x - 0.5f * b.z; p[5] = b.y - 0.5f * b.w;
        p[6] = b.x + 0.5f * b.z; p[7] = b.y + 0.5f * b.w;
        p[8] = b.z * b.w;
    }
    __syncthreads();

    if (tid >= 200) return;
    const int mL = tid * 4;                        // LDS-local m
    const int m0 = m0base + mL;                    // global m

    const float4 mcx = *(const float4*)&t_cx[mL];
    const float4 mcy = *(const float4*)&t_cy[mL];
    const float4 mw  = *(const float4*)&t_w[mL];
    const float4 mh  = *(const float4*)&t_h[mL];
    const ushort4 iv = *(const ushort4*)&t_id[mL];
    const int id0 = iv.x, id1 = iv.y, id2 = iv.z, id3 = iv.w;

    const float tx0_0 = mcx.x - 0.5f * mw.x, ty0_0 = mcy.x - 0.5f * mh.x;
    const float tx1_0 = mcx.x + 0.5f * mw.x, ty1_0 = mcy.x + 0.5f * mh.x;
    const float tx0_1 = mcx.y - 0.5f * mw.y, ty0_1 = mcy.y - 0.5f * mh.y;
    const float tx1_1 = mcx.y + 0.5f * mw.y, ty1_1 = mcy.y + 0.5f * mh.y;
    const float tx0_2 = mcx.z - 0.5f * mw.z, ty0_2 = mcy.z - 0.5f * mh.z;
    const float tx1_2 = mcx.z + 0.5f * mw.z, ty1_2 = mcy.z + 0.5f * mh.z;
    const float tx0_3 = mcx.w - 0.5f * mw.w, ty0_3 = mcy.w - 0.5f * mh.w;
    const float tx1_3 = mcx.w + 0.5f * mw.w, ty1_3 = mcy.w + 0.5f * mh.w;
    const float ta0 = mw.x * mh.x, ta1 = mw.y * mh.y;
    const float ta2 = mw.z * mh.z, ta3 = mw.w * mh.w;

    float* orow = out + (size_t)n0 * 1600 + m0;

#pragma unroll
    for (int nq = 0; nq < 4; ++nq) {
        const float4 ccq0 = *(const float4*)&ccT[id0 * 20 + nq * 4];
        const float4 ccq1 = *(const float4*)&ccT[id1 * 20 + nq * 4];
        const float4 ccq2 = *(const float4*)&ccT[id2 * 20 + nq * 4];
        const float4 ccq3 = *(const float4*)&ccT[id3 * 20 + nq * 4];
        const float c0[4] = {ccq0.x, ccq0.y, ccq0.z, ccq0.w};
        const float c1[4] = {ccq1.x, ccq1.y, ccq1.z, ccq1.w};
        const float c2[4] = {ccq2.x, ccq2.y, ccq2.z, ccq2.w};
        const float c3[4] = {ccq3.x, ccq3.y, ccq3.z, ccq3.w};
#pragma unroll
        for (int j = 0; j < 4; ++j) {
            const int n = nq * 4 + j;
            const float4 P0 = *(const float4*)&p_s[n * 12];
            const float4 P1 = *(const float4*)&p_s[n * 12 + 4];
            const float pa = p_s[n * 12 + 8];
            float4 res;
            res.x = cost_one(P0.x, P0.y, P0.z, P0.w, P1.x, P1.y, P1.z, P1.w, pa,
                             mcx.x, mcy.x, mw.x, mh.x, tx0_0, ty0_0, tx1_0, ty1_0, ta0, c0[j]);
            res.y = cost_one(P0.x, P0.y, P0.z, P0.w, P1.x, P1.y, P1.z, P1.w, pa,
                             mcx.y, mcy.y, mw.y, mh.y, tx0_1, ty0_1, tx1_1, ty1_1, ta1, c1[j]);
            res.z = cost_one(P0.x, P0.y, P0.z, P0.w, P1.x, P1.y, P1.z, P1.w, pa,
                             mcx.z, mcy.z, mw.z, mh.z, tx0_2, ty0_2, tx1_2, ty1_2, ta2, c2[j]);
            res.w = cost_one(P0.x, P0.y, P0.z, P0.w, P1.x, P1.y, P1.z, P1.w, pa,
                             mcx.w, mcy.w, mw.w, mh.w, tx0_3, ty0_3, tx1_3, ty1_3, ta3, c3[j]);
            *(float4*)(orow + (size_t)n * 1600) = res;
        }
    }
}

extern "C" void kernel_launch(void* const* d_in, const int* in_sizes, int n_in,
                              void* d_out, int out_size, void* d_ws, size_t ws_size,
                              hipStream_t stream) {
    const float* pred_logits = (const float*)d_in[0];   // [16,1024,91]
    const float* pred_boxes  = (const float*)d_in[1];   // [16,1024,4]
    const float* pred_embed  = (const float*)d_in[2];   // [16,1024,512]
    const float* text_emb    = (const float*)d_in[3];   // [91,512]
    const int*   tgt_ids     = (const int*)d_in[4];     // [1600]
    const float* tgt_bbox    = (const float*)d_in[5];   // [1600,4]
    float* out = (float*)d_out;                         // [16384,1600]

    unsigned short* te_bf = (unsigned short*)d_ws;                    // 96*512*2 = 96 KB
    float* ccombo = (float*)((char*)d_ws + 102400);                   // 16384*96*4 = 6.29 MB

    k_prep<<<96, 256, 0, stream>>>(text_emb, te_bf);
    k_class_embed<<<1024, 256, 0, stream>>>(pred_logits, pred_embed, te_bf, ccombo);
    k_cost<<<2048, 256, 0, stream>>>(pred_boxes, tgt_bbox, tgt_ids, ccombo, out);
}

// Round 4
// 67.087 us; speedup vs baseline: 2.0636x; 1.0697x over previous
//
#include <hip/hip_runtime.h>
#include <hip/hip_bf16.h>

using bf16x8 = __attribute__((ext_vector_type(8))) short;
using f32x4  = __attribute__((ext_vector_type(4))) float;

__device__ __forceinline__ unsigned short f2bf(float x) {
    unsigned int u = __float_as_uint(x);
    return (unsigned short)((u + 0x7FFFu + ((u >> 16) & 1u)) >> 16);
}

// -------------------------------------------------------------------------
// K0: pack text_embeddings [91][512] f32 -> [96][512] bf16 (rows 91..95 = 0)
// -------------------------------------------------------------------------
__global__ __launch_bounds__(256)
void k_prep(const float* __restrict__ te, unsigned short* __restrict__ te_bf) {
    const int r = blockIdx.x;            // 0..95
    for (int i = threadIdx.x; i < 512; i += 256) {
        const float v = (r < 91) ? te[(size_t)r * 512 + i] : 0.f;
        te_bf[(size_t)r * 512 + i] = f2bf(v);
    }
}

// -------------------------------------------------------------------------
// K1: ccombo[n][c] = focal(logits[n][c]) + 0.5*(1 - <v_norm[n], te[c]>)
// grid 1024, block 256 = 16 rows, 4 waves K-split (128 k each).
// -------------------------------------------------------------------------
__global__ __launch_bounds__(256)
void k_class_embed(const float* __restrict__ logits,       // [16384][91]
                   const float* __restrict__ embed,        // [16384][512]
                   const unsigned short* __restrict__ te_bf, // [96][512] bf16
                   float* __restrict__ ccombo)             // [16384][96]
{
    __shared__ float accs[4][16 * 96];     // 24576 B
    __shared__ float sq_s[4][16];

    const int tid  = threadIdx.x;
    const int lane = tid & 63;
    const int wv   = tid >> 6;             // K-chunk 0..3
    const int r16  = lane & 15;
    const int q    = lane >> 4;
    const int n0   = blockIdx.x * 16;

    f32x4 acc[6];
#pragma unroll
    for (int j = 0; j < 6; ++j) acc[j] = (f32x4){0.f, 0.f, 0.f, 0.f};
    float sumsq = 0.f;

    const float* arow = embed + (size_t)(n0 + r16) * 512 + wv * 128 + q * 8;
#pragma unroll
    for (int ks = 0; ks < 4; ++ks) {
        const float4 a0 = *(const float4*)(arow + ks * 32);
        const float4 a1 = *(const float4*)(arow + ks * 32 + 4);
        const float fv[8] = {a0.x, a0.y, a0.z, a0.w, a1.x, a1.y, a1.z, a1.w};
        bf16x8 af;
#pragma unroll
        for (int j = 0; j < 8; ++j) {
            sumsq += fv[j] * fv[j];
            af[j] = (short)f2bf(fv[j]);
        }
#pragma unroll
        for (int ct = 0; ct < 6; ++ct) {
            const bf16x8 bfr = *(const bf16x8*)(te_bf + (size_t)(ct * 16 + r16) * 512
                                                + wv * 128 + ks * 32 + q * 8);
            acc[ct] = __builtin_amdgcn_mfma_f32_16x16x32_bf16(af, bfr, acc[ct], 0, 0, 0);
        }
    }
    sumsq += __shfl_xor(sumsq, 16);
    sumsq += __shfl_xor(sumsq, 32);
    if (lane < 16) sq_s[wv][r16] = sumsq;

#pragma unroll
    for (int ct = 0; ct < 6; ++ct)
#pragma unroll
        for (int j = 0; j < 4; ++j)
            accs[wv][(q * 4 + j) * 96 + ct * 16 + r16] = acc[ct][j];
    __syncthreads();

#pragma unroll
    for (int i = 0; i < 6; ++i) {
        const int e = tid + i * 256;                 // < 1536
        const int row = e / 96, col = e - row * 96;
        float v = 0.f;
        if (col < 91) {
            const float dot = accs[0][e] + accs[1][e] + accs[2][e] + accs[3][e];
            const float rn  = rsqrtf(sq_s[0][row] + sq_s[1][row] + sq_s[2][row] + sq_s[3][row]);
            const float x = logits[(size_t)(n0 + row) * 91 + col];
            const float p = 1.f / (1.f + __expf(-x));
            const float pos = 0.25f * (1.f - p) * (1.f - p) * (-__logf(p + 1e-8f));
            const float neg = 0.75f * p * p * (-__logf(1.f - p + 1e-8f));
            v = (pos - neg) + 0.5f - 0.5f * dot * rn;
        }
        ccombo[(size_t)n0 * 96 + e] = v;
    }
}

// -------------------------------------------------------------------------
// K2: out[n][m] = ccombo[n][id[m]] + L1 - GIoU
// grid 256 n-chunks x 13 m-chunks; block 256 = 64 n x 128 m (32 grp x 4)
// Thread owns one m-group (4 boxes) in REGISTERS for all 64 n.
// m padded 1600 -> 1664: loads clamped, stores predicated.
// -------------------------------------------------------------------------
__global__ __launch_bounds__(256, 4)
void k_cost(const float* __restrict__ pboxes,   // [16384][4] cxcywh
            const float* __restrict__ tboxes,   // [1600][4]  cxcywh
            const int*   __restrict__ tids,     // [1600]
            const float* __restrict__ ccombo,   // [16384][96]
            float* __restrict__ out)            // [16384][1600]
{
    __shared__ float cc_s[64 * 96];   // 24576 B
    __shared__ float p_s[64 * 12];    //  3072 B

    const int tid    = threadIdx.x;
    const int bx     = blockIdx.x;
    const int mchunk = bx % 13;               // 13 chunks of 128 m
    const int nchunk = bx / 13;               // 256 chunks of 64 n
    const int n0     = nchunk * 64;

    // stage cc rows [n0, n0+64)
    for (int i = tid; i < 64 * 96; i += 256)
        cc_s[i] = ccombo[(size_t)n0 * 96 + i];
    // stage pred rows (raw + derived)
    if (tid < 64) {
        const float4 b = *(const float4*)(pboxes + (size_t)(n0 + tid) * 4);
        float* p = &p_s[tid * 12];
        p[0] = b.x; p[1] = b.y; p[2] = b.z; p[3] = b.w;
        p[4] = b.x - 0.5f * b.z; p[5] = b.y - 0.5f * b.w;
        p[6] = b.x + 0.5f * b.z; p[7] = b.y + 0.5f * b.w;
        p[8] = b.z * b.w;
    }

    // ---- per-thread m-group in registers
    const int m  = (mchunk * 32 + (tid & 31)) * 4;   // 0..1660
    const int mr = (m < 1600) ? m : 1596;            // clamp for safe loads
    float tcx[4], tcy[4], tw[4], th[4];
    float tx0[4], ty0[4], tx1[4], ty1[4], ta[4];
#pragma unroll
    for (int j = 0; j < 4; ++j) {
        const float4 b = *(const float4*)(tboxes + (size_t)(mr + j) * 4);
        tcx[j] = b.x; tcy[j] = b.y; tw[j] = b.z; th[j] = b.w;
        tx0[j] = b.x - 0.5f * b.z; ty0[j] = b.y - 0.5f * b.w;
        tx1[j] = b.x + 0.5f * b.z; ty1[j] = b.y + 0.5f * b.w;
        ta[j]  = b.z * b.w;
    }
    const int4 idv = *(const int4*)(tids + mr);
    const int ids[4] = {idv.x, idv.y, idv.z, idv.w};
    __syncthreads();

    const int w8 = tid >> 5;                  // 0..7 (half-wave id)
    const bool do_store = (m < 1600);

#pragma unroll
    for (int pass = 0; pass < 8; ++pass) {
        const int nl = pass * 8 + w8;         // 0..63, uniform per half-wave
        const float4 P0 = *(const float4*)&p_s[nl * 12];      // cx,cy,w,h
        const float4 P1 = *(const float4*)&p_s[nl * 12 + 4];  // x0,y0,x1,y1
        const float  pa = p_s[nl * 12 + 8];
        float res[4];
#pragma unroll
        for (int j = 0; j < 4; ++j) {
            const float cc = cc_s[nl * 96 + ids[j]];
            const float l1 = fabsf(P0.x - tcx[j]) + fabsf(P0.y - tcy[j])
                           + fabsf(P0.z - tw[j])  + fabsf(P0.w - th[j]);
            const float ix0 = fmaxf(P1.x, tx0[j]), iy0 = fmaxf(P1.y, ty0[j]);
            const float ix1 = fminf(P1.z, tx1[j]), iy1 = fminf(P1.w, ty1[j]);
            const float iw = fmaxf(ix1 - ix0, 0.f), ih = fmaxf(iy1 - iy0, 0.f);
            const float inter = iw * ih;
            const float uni = pa + ta[j] - inter;
            const float ex0 = fminf(P1.x, tx0[j]), ey0 = fminf(P1.y, ty0[j]);
            const float ex1 = fmaxf(P1.z, tx1[j]), ey1 = fmaxf(P1.w, ty1[j]);
            const float ae = (ex1 - ex0) * (ey1 - ey0);
            const float num = inter * ae - uni * (ae - uni);
            const float g = __fdividef(num, uni * ae);
            res[j] = cc + l1 - g;
        }
        if (do_store) {
            float4 r4; r4.x = res[0]; r4.y = res[1]; r4.z = res[2]; r4.w = res[3];
            *(float4*)(out + (size_t)(n0 + nl) * 1600 + m) = r4;
        }
    }
}

extern "C" void kernel_launch(void* const* d_in, const int* in_sizes, int n_in,
                              void* d_out, int out_size, void* d_ws, size_t ws_size,
                              hipStream_t stream) {
    const float* pred_logits = (const float*)d_in[0];   // [16,1024,91]
    const float* pred_boxes  = (const float*)d_in[1];   // [16,1024,4]
    const float* pred_embed  = (const float*)d_in[2];   // [16,1024,512]
    const float* text_emb    = (const float*)d_in[3];   // [91,512]
    const int*   tgt_ids     = (const int*)d_in[4];     // [1600]
    const float* tgt_bbox    = (const float*)d_in[5];   // [1600,4]
    float* out = (float*)d_out;                         // [16384,1600]

    unsigned short* te_bf = (unsigned short*)d_ws;                    // 96*512*2 = 96 KB
    float* ccombo = (float*)((char*)d_ws + 102400);                   // 16384*96*4 = 6.29 MB

    k_prep<<<96, 256, 0, stream>>>(text_emb, te_bf);
    k_class_embed<<<1024, 256, 0, stream>>>(pred_logits, pred_embed, te_bf, ccombo);
    k_cost<<<256 * 13, 256, 0, stream>>>(pred_boxes, tgt_bbox, tgt_ids, ccombo, out);
}

// Round 5
// 63.293 us; speedup vs baseline: 2.1873x; 1.0599x over previous
//
#include <hip/hip_runtime.h>
#include <hip/hip_bf16.h>

using bf16x8 = __attribute__((ext_vector_type(8))) short;
using f32x4  = __attribute__((ext_vector_type(4))) float;

__device__ __forceinline__ unsigned short f2bf(float x) {
    unsigned int u = __float_as_uint(x);
    return (unsigned short)((u + 0x7FFFu + ((u >> 16) & 1u)) >> 16);
}

// -------------------------------------------------------------------------
// K0: pack text_embeddings [91][512] f32 -> [96][512] bf16 (rows 91..95 = 0)
// -------------------------------------------------------------------------
__global__ __launch_bounds__(256)
void k_prep(const float* __restrict__ te, unsigned short* __restrict__ te_bf) {
    const int r = blockIdx.x;            // 0..95
    for (int i = threadIdx.x; i < 512; i += 256) {
        const float v = (r < 91) ? te[(size_t)r * 512 + i] : 0.f;
        te_bf[(size_t)r * 512 + i] = f2bf(v);
    }
}

// -------------------------------------------------------------------------
// K1: ccombo[n][c] = focal(logits[n][c]) + 0.5*(1 - <v_norm[n], te[c]>)
// grid 1024, block 256 = 16 rows, 4 waves K-split (128 k each).
// -------------------------------------------------------------------------
__global__ __launch_bounds__(256)
void k_class_embed(const float* __restrict__ logits,       // [16384][91]
                   const float* __restrict__ embed,        // [16384][512]
                   const unsigned short* __restrict__ te_bf, // [96][512] bf16
                   float* __restrict__ ccombo)             // [16384][96]
{
    __shared__ float accs[4][16 * 96];     // 24576 B
    __shared__ float sq_s[4][16];

    const int tid  = threadIdx.x;
    const int lane = tid & 63;
    const int wv   = tid >> 6;             // K-chunk 0..3
    const int r16  = lane & 15;
    const int q    = lane >> 4;
    const int n0   = blockIdx.x * 16;

    f32x4 acc[6];
#pragma unroll
    for (int j = 0; j < 6; ++j) acc[j] = (f32x4){0.f, 0.f, 0.f, 0.f};
    float sumsq = 0.f;

    const float* arow = embed + (size_t)(n0 + r16) * 512 + wv * 128 + q * 8;
#pragma unroll
    for (int ks = 0; ks < 4; ++ks) {
        const float4 a0 = *(const float4*)(arow + ks * 32);
        const float4 a1 = *(const float4*)(arow + ks * 32 + 4);
        const float fv[8] = {a0.x, a0.y, a0.z, a0.w, a1.x, a1.y, a1.z, a1.w};
        bf16x8 af;
#pragma unroll
        for (int j = 0; j < 8; ++j) {
            sumsq += fv[j] * fv[j];
            af[j] = (short)f2bf(fv[j]);
        }
#pragma unroll
        for (int ct = 0; ct < 6; ++ct) {
            const bf16x8 bfr = *(const bf16x8*)(te_bf + (size_t)(ct * 16 + r16) * 512
                                                + wv * 128 + ks * 32 + q * 8);
            acc[ct] = __builtin_amdgcn_mfma_f32_16x16x32_bf16(af, bfr, acc[ct], 0, 0, 0);
        }
    }
    sumsq += __shfl_xor(sumsq, 16);
    sumsq += __shfl_xor(sumsq, 32);
    if (lane < 16) sq_s[wv][r16] = sumsq;

#pragma unroll
    for (int ct = 0; ct < 6; ++ct)
#pragma unroll
        for (int j = 0; j < 4; ++j)
            accs[wv][(q * 4 + j) * 96 + ct * 16 + r16] = acc[ct][j];
    __syncthreads();

#pragma unroll
    for (int i = 0; i < 6; ++i) {
        const int e = tid + i * 256;                 // < 1536
        const int row = e / 96, col = e - row * 96;
        float v = 0.f;
        if (col < 91) {
            const float dot = accs[0][e] + accs[1][e] + accs[2][e] + accs[3][e];
            const float rn  = rsqrtf(sq_s[0][row] + sq_s[1][row] + sq_s[2][row] + sq_s[3][row]);
            const float x = logits[(size_t)(n0 + row) * 91 + col];
            const float p = 1.f / (1.f + __expf(-x));
            const float pos = 0.25f * (1.f - p) * (1.f - p) * (-__logf(p + 1e-8f));
            const float neg = 0.75f * p * p * (-__logf(1.f - p + 1e-8f));
            v = (pos - neg) + 0.5f - 0.5f * dot * rn;
        }
        ccombo[(size_t)n0 * 96 + e] = v;
    }
}

// -------------------------------------------------------------------------
// K2: out[n][m] = ccombo[n][id[m]] + L1 - GIoU
// grid 256 n-chunks x 13 m-chunks; block 256 = 64 n x 128 m (32 grp x 4)
// Thread owns one m-group (4 boxes) in registers for all 64 n.
// Enclosing box via identity: min(a,b)=a+b-max(a,b) -> ew = pw+tw-dx.
// Nontemporal stores keep the 104.8 MB out-stream from thrashing L2.
// -------------------------------------------------------------------------
__global__ __launch_bounds__(256, 4)
void k_cost(const float* __restrict__ pboxes,   // [16384][4] cxcywh
            const float* __restrict__ tboxes,   // [1600][4]  cxcywh
            const int*   __restrict__ tids,     // [1600]
            const float* __restrict__ ccombo,   // [16384][96]
            float* __restrict__ out)            // [16384][1600]
{
    __shared__ float cc_s[64 * 96];   // 24576 B
    __shared__ float p_s[64 * 12];    //  3072 B

    const int tid    = threadIdx.x;
    const int bx     = blockIdx.x;
    const int mchunk = bx % 13;               // 13 chunks of 128 m
    const int nchunk = bx / 13;               // 256 chunks of 64 n
    const int n0     = nchunk * 64;

    // stage cc rows [n0, n0+64) as float4 (6 per thread)
    {
        const f32x4* src = (const f32x4*)(ccombo + (size_t)n0 * 96);
        f32x4* dst = (f32x4*)cc_s;
#pragma unroll
        for (int i = 0; i < 6; ++i) dst[tid + i * 256] = src[tid + i * 256];
    }
    // stage pred rows (raw + derived)
    if (tid < 64) {
        const float4 b = *(const float4*)(pboxes + (size_t)(n0 + tid) * 4);
        float* p = &p_s[tid * 12];
        p[0] = b.x; p[1] = b.y; p[2] = b.z; p[3] = b.w;
        p[4] = b.x - 0.5f * b.z; p[5] = b.y - 0.5f * b.w;
        p[6] = b.x + 0.5f * b.z; p[7] = b.y + 0.5f * b.w;
        p[8] = b.z * b.w;
    }

    // ---- per-thread m-group in registers
    const int m  = (mchunk * 32 + (tid & 31)) * 4;   // 0..1660
    const int mr = (m < 1600) ? m : 1596;            // clamp for safe loads
    float tcx[4], tcy[4], tw[4], th[4];
    float tx0[4], ty0[4], tx1[4], ty1[4], ta[4];
#pragma unroll
    for (int j = 0; j < 4; ++j) {
        const float4 b = *(const float4*)(tboxes + (size_t)(mr + j) * 4);
        tcx[j] = b.x; tcy[j] = b.y; tw[j] = b.z; th[j] = b.w;
        tx0[j] = b.x - 0.5f * b.z; ty0[j] = b.y - 0.5f * b.w;
        tx1[j] = b.x + 0.5f * b.z; ty1[j] = b.y + 0.5f * b.w;
        ta[j]  = b.z * b.w;
    }
    const int4 idv = *(const int4*)(tids + mr);
    const int ids[4] = {idv.x, idv.y, idv.z, idv.w};
    __syncthreads();

    const int w8 = tid >> 5;                  // 0..7 (half-wave id)
    const bool do_store = (m < 1600);

#pragma unroll
    for (int pass = 0; pass < 8; ++pass) {
        const int nl = pass * 8 + w8;         // uniform per half-wave
        const float* pr = &p_s[nl * 12];
        const float4 P0 = *(const float4*)pr;        // cx,cy,w,h
        const float4 P1 = *(const float4*)(pr + 4);  // x0,y0,x1,y1
        const float  pa = pr[8];
        const float* ccrow = &cc_s[nl * 96];
        float res[4];
#pragma unroll
        for (int j = 0; j < 4; ++j) {
            // intersection extents (unclamped)
            const float dx = fminf(P1.z, tx1[j]) - fmaxf(P1.x, tx0[j]);
            const float dy = fminf(P1.w, ty1[j]) - fmaxf(P1.y, ty0[j]);
            const float iw = fmaxf(dx, 0.f), ih = fmaxf(dy, 0.f);
            const float inter = iw * ih;
            // enclosing box via sum identity (no extra min/max)
            const float ew = (P0.z + tw[j]) - dx;
            const float eh = (P0.w + th[j]) - dy;
            const float ae = ew * eh;
            const float uni = __builtin_fmaf(-iw, ih, pa + ta[j]);
            const float l1 = fabsf(P0.x - tcx[j]) + fabsf(P0.y - tcy[j])
                           + fabsf(P0.z - tw[j])  + fabsf(P0.w - th[j]);
            const float aemu = ae - uni;
            const float num = __builtin_fmaf(inter, ae, -(uni * aemu));
            const float g   = __fdividef(num, uni * ae);
            res[j] = (ccrow[ids[j]] + l1) - g;
        }
        if (do_store) {
            f32x4 r4 = {res[0], res[1], res[2], res[3]};
            __builtin_nontemporal_store(r4,
                (f32x4*)(out + (size_t)(n0 + nl) * 1600 + m));
        }
    }
}

extern "C" void kernel_launch(void* const* d_in, const int* in_sizes, int n_in,
                              void* d_out, int out_size, void* d_ws, size_t ws_size,
                              hipStream_t stream) {
    const float* pred_logits = (const float*)d_in[0];   // [16,1024,91]
    const float* pred_boxes  = (const float*)d_in[1];   // [16,1024,4]
    const float* pred_embed  = (const float*)d_in[2];   // [16,1024,512]
    const float* text_emb    = (const float*)d_in[3];   // [91,512]
    const int*   tgt_ids     = (const int*)d_in[4];     // [1600]
    const float* tgt_bbox    = (const float*)d_in[5];   // [1600,4]
    float* out = (float*)d_out;                         // [16384,1600]

    unsigned short* te_bf = (unsigned short*)d_ws;                    // 96*512*2 = 96 KB
    float* ccombo = (float*)((char*)d_ws + 102400);                   // 16384*96*4 = 6.29 MB

    k_prep<<<96, 256, 0, stream>>>(text_emb, te_bf);
    k_class_embed<<<1024, 256, 0, stream>>>(pred_logits, pred_embed, te_bf, ccombo);
    k_cost<<<256 * 13, 256, 0, stream>>>(pred_boxes, tgt_bbox, tgt_ids, ccombo, out);
}